// Round 10
// baseline (456.036 us; speedup 1.0000x reference)
//
#include <hip/hip_runtime.h>

#define N_E   1024
#define E_DIM 512
#define HW_   4096
#define NVEC  65536                 // 16 * 64 * 64
#define ZQ_ELEMS 33554432           // 16*512*64*64
#define BETA 0.25f

typedef _Float16 half8 __attribute__((ext_vector_type(8), aligned(16)));
typedef float f32x4 __attribute__((ext_vector_type(4)));
typedef unsigned int u32x4 __attribute__((ext_vector_type(4), aligned(16)));

union H16 { _Float16 f; unsigned short u; };
__device__ __forceinline__ unsigned short f2h(float v) { H16 h; h.f = (_Float16)v; return h.u; }

// ---------------- ynorm only (coalesced row reduce) ----------------
__global__ __launch_bounds__(64) void vq_prep(const float* __restrict__ cb,
    float* __restrict__ ynorm) {
    int j = blockIdx.x, l = threadIdx.x;
    float s = 0.f;
    for (int i = 0; i < 8; ++i) {
        float v = cb[(j << 9) + l + (i << 6)];
        s += v * v;
    }
#pragma unroll
    for (int off = 32; off > 0; off >>= 1) s += __shfl_xor(s, off);
    if (l == 0) ynorm[j] = s * 1024.f;        // scaled by 32^2 to match scaled dot
}

// ---------------- prepB: codebook -> Bf fragment-major fp16 hi/lo (x32), coalesced ----------------
// Bf region per j16 = 16384 halves (16 kchunks x 2 kinds x 512): half index G decomposes
// G = (c*2 + kind)*512 + lane*8 + e, with j = j16*16 + (lane&15), k = c*32 + (lane>>4)*8 + e.
__global__ __launch_bounds__(256) void vq_prepB(const float* __restrict__ cb,
    unsigned short* __restrict__ Bf) {
    int j16 = blockIdx.x;                  // 64 blocks
    int t = threadIdx.x;
#pragma unroll
    for (int s = 0; s < 8; ++s) {
        int G = ((s << 8) + t) << 3;
        int bi = G >> 9, w = G & 511;
        int lane = w >> 3;
        int kind = bi & 1, c = bi >> 1;
        int j = (j16 << 4) + (lane & 15);
        int k0 = (c << 5) + ((lane >> 4) << 3);
        const float* p = cb + ((long)j << 9) + k0;
        unsigned short o8[8];
#pragma unroll
        for (int e = 0; e < 8; ++e) {
            float vs = 32.f * p[e];
            _Float16 hi = (_Float16)vs;
            if (kind == 0) { H16 hh; hh.f = hi; o8[e] = hh.u; }
            else           o8[e] = f2h(vs - (float)hi);
        }
        *(u32x4*)&Bf[((long)j16 << 14) + G] = *(u32x4*)&o8[0];
    }
}

// ---------------- pack: z -> A[m][k] fp16 hi/lo (x32) + ||z||^2 block partials ----------------
__global__ __launch_bounds__(256) void vq_pack(const float* __restrict__ z,
    unsigned short* __restrict__ Ah, unsigned short* __restrict__ Al,
    float* __restrict__ zpart, int base_b, int bid0) {
    __shared__ float T[64][65];
    __shared__ float ps[4];
    int bid = blockIdx.x;
    int hw0 = (bid & 63) << 6;
    int c0 = ((bid >> 6) & 7) << 6;
    int bb = (bid >> 9) + base_b;
    int t = threadIdx.x;
    int hl = t & 63, cl = t >> 6;
    const float* zp = z + ((long)((bb << 9) + c0 + cl)) * 4096 + hw0 + hl;
#pragma unroll
    for (int i = 0; i < 16; ++i)
        T[cl + 4 * i][hl] = zp[(long)(4 * i) * 4096];
    __syncthreads();
    int hr = t >> 2, cg = (t & 3) << 4;
    long m = ((long)(bb - base_b) << 12) + hw0 + hr;   // phase-local row
    unsigned short h8[16], l8[16];
    float s = 0.f;
#pragma unroll
    for (int e = 0; e < 16; ++e) {
        float v0 = T[cg + e][hr];
        s += v0 * v0;
        float v = 32.f * v0;
        _Float16 hi = (_Float16)v;
        H16 hh; hh.f = hi;
        h8[e] = hh.u;
        l8[e] = f2h(v - (float)hi);
    }
    long o = m * 512 + c0 + cg;
    *(u32x4*)&Ah[o]     = *(u32x4*)&h8[0];
    *(u32x4*)&Ah[o + 8] = *(u32x4*)&h8[8];
    *(u32x4*)&Al[o]     = *(u32x4*)&l8[0];
    *(u32x4*)&Al[o + 8] = *(u32x4*)&l8[8];
#pragma unroll
    for (int off = 32; off > 0; off >>= 1) s += __shfl_xor(s, off);
    if ((t & 63) == 0) ps[t >> 6] = s;
    __syncthreads();
    if (t == 0) zpart[bid0 + bid] = ps[0] + ps[1] + ps[2] + ps[3];
}

// ---------------- dist: barrier-free MFMA fp16-split GEMM + fused argmin ----------------
// 256 threads (4 waves, ALL on the same 64 m-rows -> A loads L1-dedup; wave wid owns
// j16 group wid*4..wid*4+3 of each pass). Block tile 64m x 256j, 4 passes x 16 K-chunks.
// acc[4][4] = 64 AGPR -> ~140 unified regs -> 3 waves/SIMD (12 waves/CU, 3 blocks/CU).
// No LDS staging, no K-loop barriers; A from row-major Ah/Al, B from fragment-major Bf.
__global__ __launch_bounds__(256, 3) void vq_dist(
    const unsigned short* __restrict__ Ah, const unsigned short* __restrict__ Al,
    const unsigned short* __restrict__ Bf,
    const float* __restrict__ ynorm, int* __restrict__ ws_idx,
    float* __restrict__ out_idx, float* __restrict__ dpart, int mbase) {

    __shared__ float mrgd[256];
    __shared__ int   mrgj[256];
    __shared__ float psumf[4];

    const int t = threadIdx.x;
    const int l = t & 63, wid = t >> 6;     // 4 waves = 4 j16-groups
    const int lid = l & 15, kg = l >> 4;
    const int m0 = blockIdx.x << 6;         // 64 m rows per block

    // per-lane A row base: row = m0 + mt*16 + lid, halves offset row*512
    const long arow = ((long)(m0 + lid)) << 9;
    const int  koff = kg << 3;              // kg selects 8-elem group within chunk

    f32x4 acc[4][4];
    auto ZERO = [&]() {
#pragma unroll
        for (int mt = 0; mt < 4; ++mt)
#pragma unroll
            for (int jt = 0; jt < 4; ++jt) acc[mt][jt] = {0.f, 0.f, 0.f, 0.f};
    };

    auto COMPUTE = [&](int c, int p) {
        const long ao = arow + (c << 5) + koff;
        half8 ah[4], alo[4];
#pragma unroll
        for (int mt = 0; mt < 4; ++mt) {
            ah[mt]  = *(const half8*)&Ah[ao + (mt << 13)];   // row += 16 -> +16*512 halves
            alo[mt] = *(const half8*)&Al[ao + (mt << 13)];
        }
        // B fragments: block (j16, c, kind), lane offset l*8 halves
        const unsigned short* bp = Bf
            + (((long)((((p << 4) + (wid << 2)) << 4) + c)) << 10) + (l << 3);
#pragma unroll
        for (int jt = 0; jt < 4; ++jt) {
            half8 bh = *(const half8*)(bp);
            half8 bl = *(const half8*)(bp + 512);
            bp += 16384;                              // next j16: 16 chunks * 2 kinds * 512
#pragma unroll
            for (int mt = 0; mt < 4; ++mt) {
                acc[mt][jt] = __builtin_amdgcn_mfma_f32_16x16x32_f16(ah[mt],  bh, acc[mt][jt], 0, 0, 0);
                acc[mt][jt] = __builtin_amdgcn_mfma_f32_16x16x32_f16(alo[mt], bh, acc[mt][jt], 0, 0, 0);
                acc[mt][jt] = __builtin_amdgcn_mfma_f32_16x16x32_f16(ah[mt],  bl, acc[mt][jt], 0, 0, 0);
            }
        }
    };

    float bd[4][4]; int bj[4][4];           // per-thread running best (d, j)
#pragma unroll
    for (int mt = 0; mt < 4; ++mt)
#pragma unroll
        for (int r = 0; r < 4; ++r) { bd[mt][r] = 3.4e38f; bj[mt][r] = 0x7fffffff; }

    auto FOLD = [&](int p) {
#pragma unroll
        for (int jt = 0; jt < 4; ++jt) {
            int jg = (((p << 4) + (wid << 2) + jt) << 4) + lid;
            float yn = ynorm[jg];
#pragma unroll
            for (int mt = 0; mt < 4; ++mt)
#pragma unroll
                for (int r = 0; r < 4; ++r) {
                    float d = yn - 2.f * acc[mt][jt][r];
                    if (d < bd[mt][r] || (d == bd[mt][r] && jg < bj[mt][r])) {
                        bd[mt][r] = d; bj[mt][r] = jg;
                    }
                }
        }
    };

    ZERO();
    for (int s = 0; s < 64; ++s) {          // 4 passes x 16 k-chunks, NO barriers
        int p = s >> 4, c = s & 15;
        COMPUTE(c, p);
        if (c == 15) { FOLD(p); ZERO(); }
    }

    // cross-lane reduce over the 16 j-columns (lid), lexicographic (d, j)
#pragma unroll
    for (int off = 1; off < 16; off <<= 1)
#pragma unroll
        for (int mt = 0; mt < 4; ++mt)
#pragma unroll
            for (int r = 0; r < 4; ++r) {
                float od = __shfl_xor(bd[mt][r], off);
                int   oj = __shfl_xor(bj[mt][r], off);
                if (od < bd[mt][r] || (od == bd[mt][r] && oj < bj[mt][r])) {
                    bd[mt][r] = od; bj[mt][r] = oj;
                }
            }

    // merge the 4 j-wave-groups via small LDS
    if (lid == 0) {
#pragma unroll
        for (int mt = 0; mt < 4; ++mt)
#pragma unroll
            for (int r = 0; r < 4; ++r) {
                int idx = (wid << 6) + (mt << 4) + (kg << 2) + r;
                mrgd[idx] = bd[mt][r]; mrgj[idx] = bj[mt][r];
            }
    }
    __syncthreads();

    float myd = 0.f;
    if (t < 64) {                           // one thread per m row: t = mt*16+kg*4+r
        float bD = 3.4e38f; int bJ = 0x7fffffff;
#pragma unroll
        for (int wjv = 0; wjv < 4; ++wjv) {
            int idx = (wjv << 6) + t;
            float od = mrgd[idx]; int oj = mrgj[idx];
            if (od < bD || (od == bD && oj < bJ)) { bD = od; bJ = oj; }
        }
        int m = mbase + m0 + t;
        ws_idx[m] = bJ;
        out_idx[m] = (float)bJ;
        myd = bD;                           // scaled distance missing ||z||^2 (added in final)
    }
#pragma unroll
    for (int off = 32; off > 0; off >>= 1) myd += __shfl_xor(myd, off);
    if (l == 0) psumf[wid] = myd;
    __syncthreads();
    if (t == 0)
        dpart[(mbase >> 6) + blockIdx.x] = psumf[0] + psumf[1] + psumf[2] + psumf[3];
}

// ---------------- gather: pure scatter of codebook rows into (B,C,H,W) ----------------
__global__ __launch_bounds__(256) void vq_gather(const float* __restrict__ cb,
    const int* __restrict__ ws_idx, float* __restrict__ out) {
    int base = blockIdx.x * 256 + threadIdx.x;   // 2^21 threads
    int hw  = base & 4095;
    int c4g = (base >> 12) & 31;
    int b   = base >> 17;
    int j   = ws_idx[(b << 12) | hw];
#pragma unroll
    for (int it = 0; it < 4; ++it) {
        int c4 = (c4g << 2) + it;
        float4 v = ((const float4*)cb)[(j << 7) + c4];
        long zo = ((long)((b << 9) + (c4 << 2))) * 4096 + hw;
        out[zo] = v.x; out[zo + 4096] = v.y; out[zo + 8192] = v.z; out[zo + 12288] = v.w;
    }
}

// ---------------- final: loss = 1.25 * (sum(bestd)/1024 + sum||z||^2) / numel ----------------
__global__ __launch_bounds__(1024) void vq_final(const float* __restrict__ dpart,
    const float* __restrict__ zpart, float* __restrict__ out) {
    int t = threadIdx.x;
    double s = (double)dpart[t] * (1.0 / 1024.0);   // 1024 block partials
#pragma unroll
    for (int i = 0; i < 8; ++i) s += (double)zpart[t + (i << 10)];
#pragma unroll
    for (int off = 32; off > 0; off >>= 1) s += __shfl_xor(s, off);
    __shared__ double pd[16];
    if ((t & 63) == 0) pd[t >> 6] = s;
    __syncthreads();
    if (t == 0) {
        double tot = 0.0;
#pragma unroll
        for (int i = 0; i < 16; ++i) tot += pd[i];
        out[ZQ_ELEMS] = (float)(1.25 * tot / 33554432.0);
    }
}

extern "C" void kernel_launch(void* const* d_in, const int* in_sizes, int n_in,
                              void* d_out, int out_size, void* d_ws, size_t ws_size,
                              hipStream_t stream) {
    const float* z  = (const float*)d_in[0];   // (16,512,64,64) fp32
    const float* cb = (const float*)d_in[1];   // (1024,512) fp32
    float* out = (float*)d_out;                // [z_q | loss | indices(float)]
    char* ws = (char*)d_ws;

    float* ynorm    = (float*)(ws + 1024);                // 4 KB
    int*   ws_idx   = (int*)(ws + 8192);                  // 256 KB
    float* dpart    = (float*)(ws + 272 * 1024);          // 4 KB (1024 floats)
    float* zpart    = (float*)(ws + 288 * 1024);          // 32 KB (8192 floats)
    unsigned short* Bf = (unsigned short*)(ws + (1L << 20));   // 2 MB fragment-major
    const size_t base = 3L << 20;
    unsigned short* Ah = (unsigned short*)(ws + base);

    // pick M-phasing from available workspace (deterministic in ws_size)
    int nphase = 1;
    while (nphase < 16) {
        size_t Asz = (size_t)(65536 / nphase) * 512 * 2;
        if (base + 2 * Asz <= ws_size) break;
        nphase <<= 1;
    }
    size_t Asz = (size_t)(65536 / nphase) * 512 * 2;
    unsigned short* Al = (unsigned short*)(ws + base + Asz);

    vq_prep<<<N_E, 64, 0, stream>>>(cb, ynorm);
    vq_prepB<<<64, 256, 0, stream>>>(cb, Bf);
    int PM = 65536 / nphase;
    for (int p = 0; p < nphase; ++p) {
        vq_pack<<<8192 / nphase, 256, 0, stream>>>(z, Ah, Al, zpart,
                                                   p * (16 / nphase),
                                                   p * (8192 / nphase));
        vq_dist<<<PM / 64, 256, 0, stream>>>(Ah, Al, Bf, ynorm, ws_idx,
                                             out + ZQ_ELEMS + 1, dpart, p * PM);
    }
    vq_gather<<<NVEC / 256 * 32, 256, 0, stream>>>(cb, ws_idx, out);
    vq_final<<<1, 1024, 0, stream>>>(dpart, zpart, out);
}

// Round 11
// 312.314 us; speedup vs baseline: 1.4602x; 1.4602x over previous
//
#include <hip/hip_runtime.h>

#define N_E   1024
#define E_DIM 512
#define HW_   4096
#define NVEC  65536                 // 16 * 64 * 64
#define ZQ_ELEMS 33554432           // 16*512*64*64
#define BETA 0.25f

typedef _Float16 half8 __attribute__((ext_vector_type(8), aligned(16)));
typedef float f32x4 __attribute__((ext_vector_type(4)));
typedef unsigned int u32x4 __attribute__((ext_vector_type(4), aligned(16)));

union H16 { _Float16 f; unsigned short u; };
__device__ __forceinline__ unsigned short f2h(float v) { H16 h; h.f = (_Float16)v; return h.u; }

// direct-to-LDS DMA: per-lane global src, wave-uniform LDS base + lane*16
#define GLDS(gp, lp) __builtin_amdgcn_global_load_lds( \
    (const __attribute__((address_space(1))) void*)(gp), \
    (__attribute__((address_space(3))) void*)(lp), 16, 0, 0)

// ---------------- ynorm only (coalesced row reduce) ----------------
__global__ __launch_bounds__(64) void vq_prep(const float* __restrict__ cb,
    float* __restrict__ ynorm) {
    int j = blockIdx.x, l = threadIdx.x;
    float s = 0.f;
    for (int i = 0; i < 8; ++i) {
        float v = cb[(j << 9) + l + (i << 6)];
        s += v * v;
    }
#pragma unroll
    for (int off = 32; off > 0; off >>= 1) s += __shfl_xor(s, off);
    if (l == 0) ynorm[j] = s * 1024.f;        // scaled by 32^2 to match scaled dot
}

// ---------------- prepB: codebook -> Bf fragment-major fp16 hi/lo (x32), coalesced ----------------
// Bf region per j16 = 16384 halves (16 kchunks x 2 kinds x 512): half index G decomposes
// G = (c*2 + kind)*512 + lane*8 + e, with j = j16*16 + (lane&15), k = c*32 + (lane>>4)*8 + e.
__global__ __launch_bounds__(256) void vq_prepB(const float* __restrict__ cb,
    unsigned short* __restrict__ Bf) {
    int j16 = blockIdx.x;                  // 64 blocks
    int t = threadIdx.x;
#pragma unroll
    for (int s = 0; s < 8; ++s) {
        int G = ((s << 8) + t) << 3;
        int bi = G >> 9, w = G & 511;
        int lane = w >> 3;
        int kind = bi & 1, c = bi >> 1;
        int j = (j16 << 4) + (lane & 15);
        int k0 = (c << 5) + ((lane >> 4) << 3);
        const float* p = cb + ((long)j << 9) + k0;
        unsigned short o8[8];
#pragma unroll
        for (int e = 0; e < 8; ++e) {
            float vs = 32.f * p[e];
            _Float16 hi = (_Float16)vs;
            if (kind == 0) { H16 hh; hh.f = hi; o8[e] = hh.u; }
            else           o8[e] = f2h(vs - (float)hi);
        }
        *(u32x4*)&Bf[((long)j16 << 14) + G] = *(u32x4*)&o8[0];
    }
}

// ---------------- pack: z -> A[m][k] fp16 hi/lo (x32) + ||z||^2 block partials ----------------
__global__ __launch_bounds__(256) void vq_pack(const float* __restrict__ z,
    unsigned short* __restrict__ Ah, unsigned short* __restrict__ Al,
    float* __restrict__ zpart, int base_b, int bid0) {
    __shared__ float T[64][65];
    __shared__ float ps[4];
    int bid = blockIdx.x;
    int hw0 = (bid & 63) << 6;
    int c0 = ((bid >> 6) & 7) << 6;
    int bb = (bid >> 9) + base_b;
    int t = threadIdx.x;
    int hl = t & 63, cl = t >> 6;
    const float* zp = z + ((long)((bb << 9) + c0 + cl)) * 4096 + hw0 + hl;
#pragma unroll
    for (int i = 0; i < 16; ++i)
        T[cl + 4 * i][hl] = zp[(long)(4 * i) * 4096];
    __syncthreads();
    int hr = t >> 2, cg = (t & 3) << 4;
    long m = ((long)(bb - base_b) << 12) + hw0 + hr;   // phase-local row
    unsigned short h8[16], l8[16];
    float s = 0.f;
#pragma unroll
    for (int e = 0; e < 16; ++e) {
        float v0 = T[cg + e][hr];
        s += v0 * v0;
        float v = 32.f * v0;
        _Float16 hi = (_Float16)v;
        H16 hh; hh.f = hi;
        h8[e] = hh.u;
        l8[e] = f2h(v - (float)hi);
    }
    long o = m * 512 + c0 + cg;
    *(u32x4*)&Ah[o]     = *(u32x4*)&h8[0];
    *(u32x4*)&Ah[o + 8] = *(u32x4*)&h8[8];
    *(u32x4*)&Al[o]     = *(u32x4*)&l8[0];
    *(u32x4*)&Al[o + 8] = *(u32x4*)&l8[8];
#pragma unroll
    for (int off = 32; off > 0; off >>= 1) s += __shfl_xor(s, off);
    if ((t & 63) == 0) ps[t >> 6] = s;
    __syncthreads();
    if (t == 0) zpart[bid0 + bid] = ps[0] + ps[1] + ps[2] + ps[3];
}

// ---------------- dist: LDS-staged MFMA fp16-split GEMM + fused argmin ----------------
// 512 threads (8 waves: 2m x 4j), block tile 128m x 256j, 4 j-passes x 16 K-chunks of 32.
// A+B staged to LDS via global_load_lds each chunk (TD line traffic minimized; reuse
// served by the separate LDS pipe). acc[4][4]=64 AGPR, argmin best kept in LDS ->
// ~120 regs/thread -> launch_bounds(512,4) -> 16 waves/CU = 2 co-resident blocks whose
// stage/drain phases mutually hide under the other block's MFMA burst.
__global__ __launch_bounds__(512, 4) void vq_dist(
    const unsigned short* __restrict__ Ah, const unsigned short* __restrict__ Al,
    const unsigned short* __restrict__ Bf,
    const float* __restrict__ ynorm, int* __restrict__ ws_idx,
    float* __restrict__ out_idx, float* __restrict__ dpart, int mbase) {

    __shared__ _Float16 sA[128][64];     // 16 KB [m][slots: hi 0..3 | lo 4..7, XOR row&7]
    __shared__ _Float16 sB[32][512];     // 32 KB fragment-major: [jj*2+kind][512]
    __shared__ float bestd[512];         // 2 KB  [row][jw]
    __shared__ int   bestj[512];         // 2 KB
    __shared__ float psumf[8];

    const int t = threadIdx.x;
    const int l = t & 63, wid = t >> 6;
    const int lid = l & 15, kg = l >> 4;
    const int wm = (wid >> 2) << 6;         // 2 m-wave-groups of 64 rows
    const int jw = wid & 3;                 // 4 j-wave-groups of 64 cols
    const int m0 = blockIdx.x << 7;         // 128 m rows per block

    // A staging (round-8-verified map): lane l -> row r8 = l>>3, slot sl = l&7;
    // source slot st = sl ^ r8 (read-side XOR swizzle pre-applied to global source).
    const int r8 = l >> 3, sl = l & 7, st = sl ^ r8;
    const unsigned short* Asrc = (st & 4) ? Al : Ah;
    const unsigned short* gpA0 = Asrc + ((long)(m0 + (wid << 3) + r8) << 9) + ((st & 3) << 3);
    // B staging: wave stages fragments f = wid*4 .. wid*4+3 (jj = f>>1, kind = f&1)
    const long boff = (long)(l << 3);

    // init LDS running best
    bestd[t] = 3.4e38f; bestj[t] = 0x7fffffff;

    f32x4 acc[4][4];
    auto ZERO = [&]() {
#pragma unroll
        for (int mt = 0; mt < 4; ++mt)
#pragma unroll
            for (int jt = 0; jt < 4; ++jt) acc[mt][jt] = {0.f, 0.f, 0.f, 0.f};
    };

    auto STAGE = [&](int c, int p) {
        const long ao = (long)c << 5;
#pragma unroll
        for (int g = 0; g < 2; ++g)
            GLDS(gpA0 + ao + ((long)g << 15), &sA[(wid + (g << 3)) << 3][0]);
#pragma unroll
        for (int i = 0; i < 4; ++i) {
            int f = (wid << 2) + i;
            int jj = f >> 1, kind = f & 1;
            const unsigned short* src = Bf
                + ((((long)(((p << 4) + jj) << 4) + c) << 1) + kind) * 512 + boff;
            GLDS(src, &sB[f][0]);
        }
    };

    auto COMPUTE = [&]() {
        half8 ah[4], alo[4];
#pragma unroll
        for (int mt = 0; mt < 4; ++mt) {
            int row = wm + (mt << 4) + lid;
            ah[mt]  = *(const half8*)&sA[row][(kg ^ (row & 7)) << 3];
            alo[mt] = *(const half8*)&sA[row][((4 + kg) ^ (row & 7)) << 3];
        }
#pragma unroll
        for (int jt = 0; jt < 4; ++jt) {
            int fr = ((jw << 2) + jt) << 1;
            half8 bh = *(const half8*)&sB[fr][l << 3];
            half8 bl = *(const half8*)&sB[fr + 1][l << 3];
#pragma unroll
            for (int mt = 0; mt < 4; ++mt) {
                acc[mt][jt] = __builtin_amdgcn_mfma_f32_16x16x32_f16(ah[mt],  bh, acc[mt][jt], 0, 0, 0);
                acc[mt][jt] = __builtin_amdgcn_mfma_f32_16x16x32_f16(alo[mt], bh, acc[mt][jt], 0, 0, 0);
                acc[mt][jt] = __builtin_amdgcn_mfma_f32_16x16x32_f16(ah[mt],  bl, acc[mt][jt], 0, 0, 0);
            }
        }
    };

    auto FOLD = [&](int p) {
        const int jgb = (p << 8) + (jw << 6);
        float yn[4];
#pragma unroll
        for (int jt = 0; jt < 4; ++jt) yn[jt] = ynorm[jgb + (jt << 4) + lid];
#pragma unroll
        for (int mt = 0; mt < 4; ++mt)
#pragma unroll
            for (int r = 0; r < 4; ++r) {
                float bd = 3.4e38f; int bj = 0x7fffffff;
#pragma unroll
                for (int jt = 0; jt < 4; ++jt) {
                    int jg = jgb + (jt << 4) + lid;
                    float d = yn[jt] - 2.f * acc[mt][jt][r];
                    if (d < bd || (d == bd && jg < bj)) { bd = d; bj = jg; }
                }
#pragma unroll
                for (int off = 1; off < 16; off <<= 1) {
                    float od = __shfl_xor(bd, off);
                    int   oj = __shfl_xor(bj, off);
                    if (od < bd || (od == bd && oj < bj)) { bd = od; bj = oj; }
                }
                if (lid == 0) {
                    int slot = ((wm + (mt << 4) + (kg << 2) + r) << 2) + jw;
                    float D = bestd[slot]; int J = bestj[slot];
                    if (bd < D || (bd == D && bj < J)) { bestd[slot] = bd; bestj[slot] = bj; }
                }
            }
    };

    ZERO();
    __syncthreads();                        // bestd/bestj init visible

    for (int s = 0; s < 64; ++s) {          // 4 passes x 16 k-chunks
        int p = s >> 4, c = s & 15;
        STAGE(c, p);
        __syncthreads();                    // GLDS drained (vmcnt0) -> staged data visible
        COMPUTE();
        if (c == 15) { FOLD(p); ZERO(); }
        __syncthreads();                    // readers done before next stage overwrites
    }

    // final merge across the 4 j-wave slots + writeout
    float myd = 0.f;
    if (t < 128) {                          // one thread per m row
        float bD = 3.4e38f; int bJ = 0x7fffffff;
#pragma unroll
        for (int w = 0; w < 4; ++w) {
            int slot = (t << 2) + w;
            float od = bestd[slot]; int oj = bestj[slot];
            if (od < bD || (od == bD && oj < bJ)) { bD = od; bJ = oj; }
        }
        int m = mbase + m0 + t;
        ws_idx[m] = bJ;
        out_idx[m] = (float)bJ;
        myd = bD;                           // scaled distance missing ||z||^2 (added in final)
    }
#pragma unroll
    for (int off = 32; off > 0; off >>= 1) myd += __shfl_xor(myd, off);
    if (l == 0) psumf[wid] = myd;
    __syncthreads();
    if (t == 0) {
        float tot = 0.f;
#pragma unroll
        for (int i = 0; i < 8; ++i) tot += psumf[i];
        dpart[(mbase >> 7) + blockIdx.x] = tot;
    }
}

// ---------------- gather: pure scatter of codebook rows into (B,C,H,W) ----------------
__global__ __launch_bounds__(256) void vq_gather(const float* __restrict__ cb,
    const int* __restrict__ ws_idx, float* __restrict__ out) {
    int base = blockIdx.x * 256 + threadIdx.x;   // 2^21 threads
    int hw  = base & 4095;
    int c4g = (base >> 12) & 31;
    int b   = base >> 17;
    int j   = ws_idx[(b << 12) | hw];
#pragma unroll
    for (int it = 0; it < 4; ++it) {
        int c4 = (c4g << 2) + it;
        float4 v = ((const float4*)cb)[(j << 7) + c4];
        long zo = ((long)((b << 9) + (c4 << 2))) * 4096 + hw;
        out[zo] = v.x; out[zo + 4096] = v.y; out[zo + 8192] = v.z; out[zo + 12288] = v.w;
    }
}

// ---------------- final: loss = 1.25 * (sum(bestd)/1024 + sum||z||^2) / numel ----------------
__global__ __launch_bounds__(1024) void vq_final(const float* __restrict__ dpart,
    const float* __restrict__ zpart, float* __restrict__ out) {
    int t = threadIdx.x;
    double s = 0.0;
    if (t < 512) s += (double)dpart[t] * (1.0 / 1024.0);
#pragma unroll
    for (int i = 0; i < 8; ++i) s += (double)zpart[t + (i << 10)];
#pragma unroll
    for (int off = 32; off > 0; off >>= 1) s += __shfl_xor(s, off);
    __shared__ double pd[16];
    if ((t & 63) == 0) pd[t >> 6] = s;
    __syncthreads();
    if (t == 0) {
        double tot = 0.0;
#pragma unroll
        for (int i = 0; i < 16; ++i) tot += pd[i];
        out[ZQ_ELEMS] = (float)(1.25 * tot / 33554432.0);
    }
}

extern "C" void kernel_launch(void* const* d_in, const int* in_sizes, int n_in,
                              void* d_out, int out_size, void* d_ws, size_t ws_size,
                              hipStream_t stream) {
    const float* z  = (const float*)d_in[0];   // (16,512,64,64) fp32
    const float* cb = (const float*)d_in[1];   // (1024,512) fp32
    float* out = (float*)d_out;                // [z_q | loss | indices(float)]
    char* ws = (char*)d_ws;

    float* ynorm    = (float*)(ws + 1024);                // 4 KB
    int*   ws_idx   = (int*)(ws + 8192);                  // 256 KB
    float* dpart    = (float*)(ws + 272 * 1024);          // 2 KB (512 floats)
    float* zpart    = (float*)(ws + 288 * 1024);          // 32 KB (8192 floats)
    unsigned short* Bf = (unsigned short*)(ws + (1L << 20));   // 2 MB fragment-major
    const size_t base = 3L << 20;
    unsigned short* Ah = (unsigned short*)(ws + base);

    // pick M-phasing from available workspace (deterministic in ws_size)
    int nphase = 1;
    while (nphase < 16) {
        size_t Asz = (size_t)(65536 / nphase) * 512 * 2;
        if (base + 2 * Asz <= ws_size) break;
        nphase <<= 1;
    }
    size_t Asz = (size_t)(65536 / nphase) * 512 * 2;
    unsigned short* Al = (unsigned short*)(ws + base + Asz);

    vq_prep<<<N_E, 64, 0, stream>>>(cb, ynorm);
    vq_prepB<<<64, 256, 0, stream>>>(cb, Bf);
    int PM = 65536 / nphase;
    for (int p = 0; p < nphase; ++p) {
        vq_pack<<<8192 / nphase, 256, 0, stream>>>(z, Ah, Al, zpart,
                                                   p * (16 / nphase),
                                                   p * (8192 / nphase));
        vq_dist<<<PM / 128, 512, 0, stream>>>(Ah, Al, Bf, ynorm, ws_idx,
                                              out + ZQ_ELEMS + 1, dpart, p * PM);
    }
    vq_gather<<<NVEC / 256 * 32, 256, 0, stream>>>(cb, ws_idx, out);
    vq_final<<<1, 1024, 0, stream>>>(dpart, zpart, out);
}

// Round 12
// 301.785 us; speedup vs baseline: 1.5111x; 1.0349x over previous
//
#include <hip/hip_runtime.h>

#define N_E   1024
#define E_DIM 512
#define HW_   4096
#define NVEC  65536                 // 16 * 64 * 64
#define ZQ_ELEMS 33554432           // 16*512*64*64
#define BETA 0.25f

typedef _Float16 half8 __attribute__((ext_vector_type(8), aligned(16)));
typedef float f32x4 __attribute__((ext_vector_type(4)));
typedef unsigned int u32x4 __attribute__((ext_vector_type(4), aligned(16)));

union H16 { _Float16 f; unsigned short u; };
__device__ __forceinline__ unsigned short f2h(float v) { H16 h; h.f = (_Float16)v; return h.u; }

// direct-to-LDS DMA: per-lane global src, wave-uniform LDS base + lane*16
#define GLDS(gp, lp) __builtin_amdgcn_global_load_lds( \
    (const __attribute__((address_space(1))) void*)(gp), \
    (__attribute__((address_space(3))) void*)(lp), 16, 0, 0)

// ---------------- ynorm only (coalesced row reduce) ----------------
__global__ __launch_bounds__(64) void vq_prep(const float* __restrict__ cb,
    float* __restrict__ ynorm) {
    int j = blockIdx.x, l = threadIdx.x;
    float s = 0.f;
    for (int i = 0; i < 8; ++i) {
        float v = cb[(j << 9) + l + (i << 6)];
        s += v * v;
    }
#pragma unroll
    for (int off = 32; off > 0; off >>= 1) s += __shfl_xor(s, off);
    if (l == 0) ynorm[j] = s * 1024.f;        // scaled by 32^2 to match scaled dot
}

// ---------------- prepB: codebook -> Bf fragment-major fp16 hi/lo (x32), coalesced ----------------
// Bf region per j16 = 16384 halves (16 kchunks x 2 kinds x 512): half index G decomposes
// G = (c*2 + kind)*512 + lane*8 + e, with j = j16*16 + (lane&15), k = c*32 + (lane>>4)*8 + e.
__global__ __launch_bounds__(256) void vq_prepB(const float* __restrict__ cb,
    unsigned short* __restrict__ Bf) {
    int j16 = blockIdx.x;                  // 64 blocks
    int t = threadIdx.x;
#pragma unroll
    for (int s = 0; s < 8; ++s) {
        int G = ((s << 8) + t) << 3;
        int bi = G >> 9, w = G & 511;
        int lane = w >> 3;
        int kind = bi & 1, c = bi >> 1;
        int j = (j16 << 4) + (lane & 15);
        int k0 = (c << 5) + ((lane >> 4) << 3);
        const float* p = cb + ((long)j << 9) + k0;
        unsigned short o8[8];
#pragma unroll
        for (int e = 0; e < 8; ++e) {
            float vs = 32.f * p[e];
            _Float16 hi = (_Float16)vs;
            if (kind == 0) { H16 hh; hh.f = hi; o8[e] = hh.u; }
            else           o8[e] = f2h(vs - (float)hi);
        }
        *(u32x4*)&Bf[((long)j16 << 14) + G] = *(u32x4*)&o8[0];
    }
}

// ---------------- pack: z -> A[m][k] fp16 hi/lo (x32) + ||z||^2 block partials ----------------
__global__ __launch_bounds__(256) void vq_pack(const float* __restrict__ z,
    unsigned short* __restrict__ Ah, unsigned short* __restrict__ Al,
    float* __restrict__ zpart, int base_b, int bid0) {
    __shared__ float T[64][65];
    __shared__ float ps[4];
    int bid = blockIdx.x;
    int hw0 = (bid & 63) << 6;
    int c0 = ((bid >> 6) & 7) << 6;
    int bb = (bid >> 9) + base_b;
    int t = threadIdx.x;
    int hl = t & 63, cl = t >> 6;
    const float* zp = z + ((long)((bb << 9) + c0 + cl)) * 4096 + hw0 + hl;
#pragma unroll
    for (int i = 0; i < 16; ++i)
        T[cl + 4 * i][hl] = zp[(long)(4 * i) * 4096];
    __syncthreads();
    int hr = t >> 2, cg = (t & 3) << 4;
    long m = ((long)(bb - base_b) << 12) + hw0 + hr;   // phase-local row
    unsigned short h8[16], l8[16];
    float s = 0.f;
#pragma unroll
    for (int e = 0; e < 16; ++e) {
        float v0 = T[cg + e][hr];
        s += v0 * v0;
        float v = 32.f * v0;
        _Float16 hi = (_Float16)v;
        H16 hh; hh.f = hi;
        h8[e] = hh.u;
        l8[e] = f2h(v - (float)hi);
    }
    long o = m * 512 + c0 + cg;
    *(u32x4*)&Ah[o]     = *(u32x4*)&h8[0];
    *(u32x4*)&Ah[o + 8] = *(u32x4*)&h8[8];
    *(u32x4*)&Al[o]     = *(u32x4*)&l8[0];
    *(u32x4*)&Al[o + 8] = *(u32x4*)&l8[8];
#pragma unroll
    for (int off = 32; off > 0; off >>= 1) s += __shfl_xor(s, off);
    if ((t & 63) == 0) ps[t >> 6] = s;
    __syncthreads();
    if (t == 0) zpart[bid0 + bid] = ps[0] + ps[1] + ps[2] + ps[3];
}

// ---------------- dist: MFMA fp16-split GEMM + fused argmin ----------------
// 256 threads (4 waves, all on the same 64 m-rows; wave wid owns j16 quad wid*4..+3
// of each pass). Block tile 64m x 256j, 4 passes x 16 K-chunks of 32.
// A: double-buffered LDS (2x8 KB) via global_load_lds, staged BEFORE compute so the
// DMA latency hides under MFMA + B-loads; ONE barrier per chunk.
// B: register fragments straight from fragment-major Bf (L2-resident, coalesced).
// acc[4][4]=64 AGPR + LDS running-best -> ~128 unified regs -> 4 waves/SIMD,
// 4 independent blocks/CU fill each other's drain tails.
__global__ __launch_bounds__(256, 4) void vq_dist(
    const unsigned short* __restrict__ Ah, const unsigned short* __restrict__ Al,
    const unsigned short* __restrict__ Bf,
    const float* __restrict__ ynorm, int* __restrict__ ws_idx,
    float* __restrict__ out_idx, float* __restrict__ dpart, int mbase) {

    __shared__ _Float16 sA[2][64][64];   // 16 KB [buf][row][slots: hi 0..3 | lo 4..7, XOR row&7]
    __shared__ float bestd[256];         // [row][jw]
    __shared__ int   bestj[256];
    __shared__ float psumf[4];

    const int t = threadIdx.x;
    const int l = t & 63, wid = t >> 6;     // 4 waves = 4 j-quads
    const int lid = l & 15, kg = l >> 4;
    const int m0 = blockIdx.x << 6;         // 64 m rows per block

    // A staging (round-8/11-verified map): lane l -> row r8 = l>>3, slot sl = l&7;
    // source slot st = sl ^ r8 (read-side XOR swizzle pre-applied to global source).
    // rows covered: m0 + wid*8 + r8 + g*32, g<2.
    const int r8 = l >> 3, sl = l & 7, st = sl ^ r8;
    const unsigned short* Asrc = (st & 4) ? Al : Ah;
    const unsigned short* gpA0 = Asrc + ((long)(m0 + (wid << 3) + r8) << 9) + ((st & 3) << 3);

    auto STAGE = [&](int buf, int c) {
        const long ao = (long)c << 5;                  // k-chunk offset (halves)
#pragma unroll
        for (int g = 0; g < 2; ++g)                    // 32-row stride = 32*512 halves
            GLDS(gpA0 + ao + ((long)g << 14), &sA[buf][(wid + (g << 2)) << 3][0]);
    };

    f32x4 acc[4][4];
    auto ZERO = [&]() {
#pragma unroll
        for (int mt = 0; mt < 4; ++mt)
#pragma unroll
            for (int jt = 0; jt < 4; ++jt) acc[mt][jt] = {0.f, 0.f, 0.f, 0.f};
    };

    auto COMPUTE = [&](int buf, int c, int p) {
        half8 ah[4], alo[4];
#pragma unroll
        for (int mt = 0; mt < 4; ++mt) {
            int row = (mt << 4) + lid;
            ah[mt]  = *(const half8*)&sA[buf][row][(kg ^ (row & 7)) << 3];
            alo[mt] = *(const half8*)&sA[buf][row][((4 + kg) ^ (row & 7)) << 3];
        }
        // B fragments: block (j16 = p*16 + wid*4 + jt, c, kind), lane offset l*8 halves
        const unsigned short* bp = Bf
            + (((long)((((p << 4) + (wid << 2)) << 4) + c)) << 10) + (l << 3);
#pragma unroll
        for (int jt = 0; jt < 4; ++jt) {
            half8 bh = *(const half8*)(bp);
            half8 bl = *(const half8*)(bp + 512);
            bp += 16384;                              // next j16: 16 chunks * 2 kinds * 512
#pragma unroll
            for (int mt = 0; mt < 4; ++mt) {
                acc[mt][jt] = __builtin_amdgcn_mfma_f32_16x16x32_f16(ah[mt],  bh, acc[mt][jt], 0, 0, 0);
                acc[mt][jt] = __builtin_amdgcn_mfma_f32_16x16x32_f16(alo[mt], bh, acc[mt][jt], 0, 0, 0);
                acc[mt][jt] = __builtin_amdgcn_mfma_f32_16x16x32_f16(ah[mt],  bl, acc[mt][jt], 0, 0, 0);
            }
        }
    };

    auto FOLD = [&](int p) {
        const int jgb = (p << 8) + (wid << 6);
        float yn[4];
#pragma unroll
        for (int jt = 0; jt < 4; ++jt) yn[jt] = ynorm[jgb + (jt << 4) + lid];
#pragma unroll
        for (int mt = 0; mt < 4; ++mt)
#pragma unroll
            for (int r = 0; r < 4; ++r) {
                float bd = 3.4e38f; int bj = 0x7fffffff;
#pragma unroll
                for (int jt = 0; jt < 4; ++jt) {
                    int jg = jgb + (jt << 4) + lid;
                    float d = yn[jt] - 2.f * acc[mt][jt][r];
                    if (d < bd || (d == bd && jg < bj)) { bd = d; bj = jg; }
                }
#pragma unroll
                for (int off = 1; off < 16; off <<= 1) {
                    float od = __shfl_xor(bd, off);
                    int   oj = __shfl_xor(bj, off);
                    if (od < bd || (od == bd && oj < bj)) { bd = od; bj = oj; }
                }
                if (lid == 0) {
                    int slot = (((mt << 4) + (kg << 2) + r) << 2) + wid;
                    float D = bestd[slot]; int J = bestj[slot];
                    if (bd < D || (bd == D && bj < J)) { bestd[slot] = bd; bestj[slot] = bj; }
                }
            }
    };

    bestd[t] = 3.4e38f; bestj[t] = 0x7fffffff;
    ZERO();
    STAGE(0, 0);
    __syncthreads();                        // chunk 0 staged + best init visible

    int buf = 0;
    for (int s = 0; s < 64; ++s) {          // 4 passes x 16 k-chunks, 1 barrier/chunk
        int p = s >> 4, c = s & 15;
        if (s < 63) STAGE(buf ^ 1, (s + 1) & 15);   // issue next-chunk DMA first
        COMPUTE(buf, c, p);                 // hides DMA latency under MFMA + B loads
        if (c == 15) { FOLD(p); ZERO(); }
        __syncthreads();                    // vmcnt(0) drain covered by COMPUTE
        buf ^= 1;
    }

    // final merge across the 4 j-wave slots + writeout (one thread per m row)
    float myd = 0.f;
    if (t < 64) {
        float bD = 3.4e38f; int bJ = 0x7fffffff;
#pragma unroll
        for (int w = 0; w < 4; ++w) {
            int slot = (t << 2) + w;
            float od = bestd[slot]; int oj = bestj[slot];
            if (od < bD || (od == bD && oj < bJ)) { bD = od; bJ = oj; }
        }
        int m = mbase + m0 + t;
        ws_idx[m] = bJ;
        out_idx[m] = (float)bJ;
        myd = bD;                           // scaled distance missing ||z||^2 (added in final)
    }
#pragma unroll
    for (int off = 32; off > 0; off >>= 1) myd += __shfl_xor(myd, off);
    if (l == 0) psumf[wid] = myd;
    __syncthreads();
    if (t == 0)
        dpart[(mbase >> 6) + blockIdx.x] = psumf[0] + psumf[1] + psumf[2] + psumf[3];
}

// ---------------- gather: pure scatter of codebook rows into (B,C,H,W) ----------------
__global__ __launch_bounds__(256) void vq_gather(const float* __restrict__ cb,
    const int* __restrict__ ws_idx, float* __restrict__ out) {
    int base = blockIdx.x * 256 + threadIdx.x;   // 2^21 threads
    int hw  = base & 4095;
    int c4g = (base >> 12) & 31;
    int b   = base >> 17;
    int j   = ws_idx[(b << 12) | hw];
#pragma unroll
    for (int it = 0; it < 4; ++it) {
        int c4 = (c4g << 2) + it;
        float4 v = ((const float4*)cb)[(j << 7) + c4];
        long zo = ((long)((b << 9) + (c4 << 2))) * 4096 + hw;
        out[zo] = v.x; out[zo + 4096] = v.y; out[zo + 8192] = v.z; out[zo + 12288] = v.w;
    }
}

// ---------------- final: loss = 1.25 * (sum(bestd)/1024 + sum||z||^2) / numel ----------------
__global__ __launch_bounds__(1024) void vq_final(const float* __restrict__ dpart,
    const float* __restrict__ zpart, float* __restrict__ out) {
    int t = threadIdx.x;
    double s = (double)dpart[t] * (1.0 / 1024.0);   // 1024 block partials
#pragma unroll
    for (int i = 0; i < 8; ++i) s += (double)zpart[t + (i << 10)];
#pragma unroll
    for (int off = 32; off > 0; off >>= 1) s += __shfl_xor(s, off);
    __shared__ double pd[16];
    if ((t & 63) == 0) pd[t >> 6] = s;
    __syncthreads();
    if (t == 0) {
        double tot = 0.0;
#pragma unroll
        for (int i = 0; i < 16; ++i) tot += pd[i];
        out[ZQ_ELEMS] = (float)(1.25 * tot / 33554432.0);
    }
}

extern "C" void kernel_launch(void* const* d_in, const int* in_sizes, int n_in,
                              void* d_out, int out_size, void* d_ws, size_t ws_size,
                              hipStream_t stream) {
    const float* z  = (const float*)d_in[0];   // (16,512,64,64) fp32
    const float* cb = (const float*)d_in[1];   // (1024,512) fp32
    float* out = (float*)d_out;                // [z_q | loss | indices(float)]
    char* ws = (char*)d_ws;

    float* ynorm    = (float*)(ws + 1024);                // 4 KB
    int*   ws_idx   = (int*)(ws + 8192);                  // 256 KB
    float* dpart    = (float*)(ws + 272 * 1024);          // 4 KB (1024 floats)
    float* zpart    = (float*)(ws + 288 * 1024);          // 32 KB (8192 floats)
    unsigned short* Bf = (unsigned short*)(ws + (1L << 20));   // 2 MB fragment-major
    const size_t base = 3L << 20;
    unsigned short* Ah = (unsigned short*)(ws + base);

    // pick M-phasing from available workspace (deterministic in ws_size)
    int nphase = 1;
    while (nphase < 16) {
        size_t Asz = (size_t)(65536 / nphase) * 512 * 2;
        if (base + 2 * Asz <= ws_size) break;
        nphase <<= 1;
    }
    size_t Asz = (size_t)(65536 / nphase) * 512 * 2;
    unsigned short* Al = (unsigned short*)(ws + base + Asz);

    vq_prep<<<N_E, 64, 0, stream>>>(cb, ynorm);
    vq_prepB<<<64, 256, 0, stream>>>(cb, Bf);
    int PM = 65536 / nphase;
    for (int p = 0; p < nphase; ++p) {
        vq_pack<<<8192 / nphase, 256, 0, stream>>>(z, Ah, Al, zpart,
                                                   p * (16 / nphase),
                                                   p * (8192 / nphase));
        vq_dist<<<PM / 64, 256, 0, stream>>>(Ah, Al, Bf, ynorm, ws_idx,
                                             out + ZQ_ELEMS + 1, dpart, p * PM);
    }
    vq_gather<<<NVEC / 256 * 32, 256, 0, stream>>>(cb, ws_idx, out);
    vq_final<<<1, 1024, 0, stream>>>(dpart, zpart, out);
}

// Round 13
// 225.490 us; speedup vs baseline: 2.0224x; 1.3384x over previous
//
#include <hip/hip_runtime.h>

#define N_E   1024
#define E_DIM 512
#define HW_   4096
#define NVEC  65536                 // 16 * 64 * 64
#define ZQ_ELEMS 33554432           // 16*512*64*64
#define BETA 0.25f
#define DELTA 256.0f                // scaled (x1024) refine margin, ~18 sigma of hi-only error

typedef _Float16 half8 __attribute__((ext_vector_type(8), aligned(16)));
typedef float f32x4 __attribute__((ext_vector_type(4)));
typedef unsigned int u32x4 __attribute__((ext_vector_type(4), aligned(16)));

union H16 { _Float16 f; unsigned short u; };
__device__ __forceinline__ unsigned short f2h(float v) { H16 h; h.f = (_Float16)v; return h.u; }

// direct-to-LDS DMA: per-lane global src, wave-uniform LDS base + lane*16
#define GLDS(gp, lp) __builtin_amdgcn_global_load_lds( \
    (const __attribute__((address_space(1))) void*)(gp), \
    (__attribute__((address_space(3))) void*)(lp), 16, 0, 0)

// ---------------- ynorm only (coalesced row reduce) ----------------
__global__ __launch_bounds__(64) void vq_prep(const float* __restrict__ cb,
    float* __restrict__ ynorm) {
    int j = blockIdx.x, l = threadIdx.x;
    float s = 0.f;
    for (int i = 0; i < 8; ++i) {
        float v = cb[(j << 9) + l + (i << 6)];
        s += v * v;
    }
#pragma unroll
    for (int off = 32; off > 0; off >>= 1) s += __shfl_xor(s, off);
    if (l == 0) ynorm[j] = s * 1024.f;        // scaled by 32^2 to match scaled dot
}

// ---------------- prepB: codebook -> Bf fragment-major fp16 HI only (x32) ----------------
// Per j16 block = 8192 halves (16 kchunks x 512): half index G = c*512 + lane*8 + e,
// j = j16*16 + (lane&15), k = c*32 + (lane>>4)*8 + e.  Reader stride per j16 = 1<<13.
__global__ __launch_bounds__(256) void vq_prepB(const float* __restrict__ cb,
    unsigned short* __restrict__ Bf) {
    int j16 = blockIdx.x;                  // 64 blocks
    int t = threadIdx.x;
#pragma unroll
    for (int s = 0; s < 4; ++s) {
        int G = ((s << 8) + t) << 3;
        int c = G >> 9, w = G & 511;
        int lane = w >> 3;
        int j = (j16 << 4) + (lane & 15);
        int k0 = (c << 5) + ((lane >> 4) << 3);
        const float* p = cb + ((long)j << 9) + k0;
        unsigned short o8[8];
#pragma unroll
        for (int e = 0; e < 8; ++e) {
            H16 hh; hh.f = (_Float16)(32.f * p[e]);
            o8[e] = hh.u;
        }
        *(u32x4*)&Bf[((long)j16 << 13) + G] = *(u32x4*)&o8[0];
    }
}

// ---------------- pack: z -> Ah[m][k] fp16 hi (x32) + ||z||^2 block partials ----------------
__global__ __launch_bounds__(256) void vq_pack(const float* __restrict__ z,
    unsigned short* __restrict__ Ah,
    float* __restrict__ zpart, int base_b, int bid0) {
    __shared__ float T[64][65];
    __shared__ float ps[4];
    int bid = blockIdx.x;
    int hw0 = (bid & 63) << 6;
    int c0 = ((bid >> 6) & 7) << 6;
    int bb = (bid >> 9) + base_b;
    int t = threadIdx.x;
    int hl = t & 63, cl = t >> 6;
    const float* zp = z + ((long)((bb << 9) + c0 + cl)) * 4096 + hw0 + hl;
#pragma unroll
    for (int i = 0; i < 16; ++i)
        T[cl + 4 * i][hl] = zp[(long)(4 * i) * 4096];
    __syncthreads();
    int hr = t >> 2, cg = (t & 3) << 4;
    long m = ((long)(bb - base_b) << 12) + hw0 + hr;   // phase-local row
    unsigned short h8[16];
    float s = 0.f;
#pragma unroll
    for (int e = 0; e < 16; ++e) {
        float v0 = T[cg + e][hr];
        s += v0 * v0;
        H16 hh; hh.f = (_Float16)(32.f * v0);
        h8[e] = hh.u;
    }
    long o = m * 512 + c0 + cg;
    *(u32x4*)&Ah[o]     = *(u32x4*)&h8[0];
    *(u32x4*)&Ah[o + 8] = *(u32x4*)&h8[8];
#pragma unroll
    for (int off = 32; off > 0; off >>= 1) s += __shfl_xor(s, off);
    if ((t & 63) == 0) ps[t >> 6] = s;
    __syncthreads();
    if (t == 0) zpart[bid0 + bid] = ps[0] + ps[1] + ps[2] + ps[3];
}

// lexicographic merge of two sorted top-2 sets (disjoint j)
#define MERGE2(d1, j1, d2, j2, od1, oj1, od2, oj2) do {                    \
    bool _ow = (od1) < (d1) || ((od1) == (d1) && (oj1) < (j1));            \
    float _nd1 = _ow ? (od1) : (d1); int _nj1 = _ow ? (oj1) : (j1);        \
    float _cd  = _ow ? (d1) : (od1); int _cj  = _ow ? (j1) : (oj1);        \
    float _sd  = _ow ? (od2) : (d2); int _sj  = _ow ? (oj2) : (j2);        \
    bool _cw = _cd < _sd || (_cd == _sd && _cj < _sj);                     \
    (d1) = _nd1; (j1) = _nj1;                                              \
    (d2) = _cw ? _cd : _sd; (j2) = _cw ? _cj : _sj;                        \
} while (0)

// ---------------- dist: hi-only MFMA GEMM + fused top-2 argmin ----------------
// 256 threads (4 waves on the same 64 m-rows; wave wid owns j16 quad wid*4..+3 per pass).
// Block tile 64m x 256j, 4 passes x 8 chunk-PAIRS (K=64 per pair). A-hi double-buffered
// LDS (2x8 KB) via global_load_lds (slots 0..3 = even chunk, 4..7 = odd chunk, XOR row&7);
// B-hi register fragments from L2. Running top-2 per row in LDS (keeps VGPR <= 64).
__global__ __launch_bounds__(256, 4) void vq_dist(
    const unsigned short* __restrict__ Ah, const unsigned short* __restrict__ Bf,
    const float* __restrict__ ynorm, int* __restrict__ ws_idx,
    float* __restrict__ out_idx, float* __restrict__ bd1g,
    float* __restrict__ bd2g, int* __restrict__ bj2g, int mbase) {

    __shared__ _Float16 sA[2][64][64];   // 16 KB
    __shared__ float b1d[256], b2d[256];
    __shared__ int   b1j[256], b2j[256];

    const int t = threadIdx.x;
    const int l = t & 63, wid = t >> 6;
    const int lid = l & 15, kg = l >> 4;
    const int m0 = blockIdx.x << 6;

    // A staging map: lane l -> row r8 = l>>3, LDS slot sl = l&7; source slot st = sl^r8.
    // st>>2 = chunk parity (0: even chunk, 1: odd), st&3 = 8-half group within chunk.
    const int r8 = l >> 3, sl = l & 7, st = sl ^ r8;
    const unsigned short* gpA0 = Ah + ((long)(m0 + (wid << 3) + r8) << 9)
                                    + ((st & 4) << 3) + ((st & 3) << 3);

    auto STAGE = [&](int buf, int cpair) {
        const long ao = (long)cpair << 6;              // 2 chunks = 64 halves
#pragma unroll
        for (int g = 0; g < 2; ++g)                    // 32-row stride = 1<<14 halves
            GLDS(gpA0 + ao + ((long)g << 14), &sA[buf][(wid + (g << 2)) << 3][0]);
    };

    f32x4 acc[4][4];
    auto ZERO = [&]() {
#pragma unroll
        for (int mt = 0; mt < 4; ++mt)
#pragma unroll
            for (int jt = 0; jt < 4; ++jt) acc[mt][jt] = {0.f, 0.f, 0.f, 0.f};
    };

    auto COMPUTE = [&](int buf, int sub, int c, int p) {
        half8 ah[4];
        const int q0 = sub << 2;
#pragma unroll
        for (int mt = 0; mt < 4; ++mt) {
            int row = (mt << 4) + lid;
            ah[mt] = *(const half8*)&sA[buf][row][((q0 + kg) ^ (row & 7)) << 3];
        }
        // B-hi fragments: (j16 = p*16 + wid*4 + jt, chunk c); lane offset l*8 halves
        long fb = (((long)(((p << 4) + (wid << 2)) << 4) + c) << 9) + (l << 3);
        const unsigned short* bp = Bf + fb;
#pragma unroll
        for (int jt = 0; jt < 4; ++jt) {
            half8 bh = *(const half8*)(bp);
            bp += 8192;                                // next j16: 16 chunks * 512
#pragma unroll
            for (int mt = 0; mt < 4; ++mt)
                acc[mt][jt] = __builtin_amdgcn_mfma_f32_16x16x32_f16(ah[mt], bh, acc[mt][jt], 0, 0, 0);
        }
    };

    auto FOLD = [&](int p) {
        const int jgb = (p << 8) + (wid << 6);
        float yn[4];
#pragma unroll
        for (int jt = 0; jt < 4; ++jt) yn[jt] = ynorm[jgb + (jt << 4) + lid];
#pragma unroll
        for (int mt = 0; mt < 4; ++mt)
#pragma unroll
            for (int r = 0; r < 4; ++r) {
                float d1 = 3.4e38f, d2 = 3.4e38f;
                int   i1 = 0x7fffffff, i2 = 0x7fffffff;
#pragma unroll
                for (int jt = 0; jt < 4; ++jt) {
                    int jg = jgb + (jt << 4) + lid;
                    float d = yn[jt] - 2.f * acc[mt][jt][r];
                    bool w = d < d1 || (d == d1 && jg < i1);
                    if (w) { d2 = d1; i2 = i1; d1 = d; i1 = jg; }
                    else if (d < d2 || (d == d2 && jg < i2)) { d2 = d; i2 = jg; }
                }
#pragma unroll
                for (int off = 1; off < 16; off <<= 1) {
                    float od1 = __shfl_xor(d1, off), od2 = __shfl_xor(d2, off);
                    int   oi1 = __shfl_xor(i1, off), oi2 = __shfl_xor(i2, off);
                    MERGE2(d1, i1, d2, i2, od1, oi1, od2, oi2);
                }
                if (lid == 0) {
                    int slot = (((mt << 4) + (kg << 2) + r) << 2) + wid;
                    float D1 = b1d[slot], D2 = b2d[slot];
                    int   J1 = b1j[slot], J2 = b2j[slot];
                    MERGE2(D1, J1, D2, J2, d1, i1, d2, i2);
                    b1d[slot] = D1; b1j[slot] = J1;
                    b2d[slot] = D2; b2j[slot] = J2;
                }
            }
    };

    b1d[t] = 3.4e38f; b2d[t] = 3.4e38f;
    b1j[t] = 0x7fffffff; b2j[t] = 0x7fffffff;
    ZERO();
    STAGE(0, 0);
    __syncthreads();                        // chunk-pair 0 staged + LDS init visible

    int buf = 0;
    for (int cp = 0; cp < 32; ++cp) {       // 4 passes x 8 pairs, 1 barrier/pair
        int p = cp >> 3, pc = cp & 7;
        if (cp < 31) STAGE(buf ^ 1, (cp + 1) & 7);   // A repeats every pass
        COMPUTE(buf, 0, (pc << 1),     p);
        COMPUTE(buf, 1, (pc << 1) + 1, p);
        if (pc == 7) { FOLD(p); ZERO(); }
        __syncthreads();                    // vmcnt drain covered by COMPUTE
        buf ^= 1;
    }

    // final merge across 4 wave slots (one thread per m row) + writeout
    if (t < 64) {
        float D1 = 3.4e38f, D2 = 3.4e38f;
        int   J1 = 0x7fffffff, J2 = 0x7fffffff;
#pragma unroll
        for (int w = 0; w < 4; ++w) {
            int slot = (t << 2) + w;
            MERGE2(D1, J1, D2, J2, b1d[slot], b1j[slot], b2d[slot], b2j[slot]);
        }
        int m = mbase + m0 + t;
        ws_idx[m]  = J1;
        out_idx[m] = (float)J1;
        bd1g[m] = D1;                       // scaled; missing ||z||^2 (added in final)
        bd2g[m] = D2;
        bj2g[m] = J2;
    }
}

// ---------------- refine: exact fp32 recheck of rows with hi-only gap <= DELTA ----------------
__global__ __launch_bounds__(256) void vq_refine(const float* __restrict__ z,
    const float* __restrict__ cb, const float* __restrict__ ynorm,
    const float* __restrict__ bd2, const int* __restrict__ bj2,
    int* __restrict__ ws_idx, float* __restrict__ out_idx, float* __restrict__ bd1) {
    int l = threadIdx.x & 63;
    int wv = (blockIdx.x << 2) + (threadIdx.x >> 6);   // 4096 waves
    for (int m = wv; m < NVEC; m += 4096) {
        float d1 = bd1[m];
        if (bd2[m] - d1 > DELTA) continue;             // certain: keep pass-1 result
        int j1 = ws_idx[m], j2 = bj2[m];
        const float* zr = z + ((long)(m >> 12) << 21) + (m & 4095);
        const float* c1 = cb + ((long)j1 << 9);
        const float* c2 = cb + ((long)j2 << 9);
        float s1 = 0.f, s2 = 0.f;
#pragma unroll
        for (int e = 0; e < 8; ++e) {
            int c = (l << 3) + e;
            float a = zr[(long)c << 12];
            s1 = fmaf(a, c1[c], s1);
            s2 = fmaf(a, c2[c], s2);
        }
#pragma unroll
        for (int off = 32; off > 0; off >>= 1) {
            s1 += __shfl_xor(s1, off);
            s2 += __shfl_xor(s2, off);
        }
        float de1 = ynorm[j1] - 2048.f * s1;           // scaled: 1024*(||y||^2 - 2 z.y)
        float de2 = ynorm[j2] - 2048.f * s2;
        bool take2 = de2 < de1 || (de2 == de1 && j2 < j1);
        if (l == 0) {
            if (take2) { ws_idx[m] = j2; out_idx[m] = (float)j2; bd1[m] = de2; }
            else       { bd1[m] = de1; }
        }
    }
}

// ---------------- gather: pure scatter of codebook rows into (B,C,H,W) ----------------
__global__ __launch_bounds__(256) void vq_gather(const float* __restrict__ cb,
    const int* __restrict__ ws_idx, float* __restrict__ out) {
    int base = blockIdx.x * 256 + threadIdx.x;   // 2^21 threads
    int hw  = base & 4095;
    int c4g = (base >> 12) & 31;
    int b   = base >> 17;
    int j   = ws_idx[(b << 12) | hw];
#pragma unroll
    for (int it = 0; it < 4; ++it) {
        int c4 = (c4g << 2) + it;
        float4 v = ((const float4*)cb)[(j << 7) + c4];
        long zo = ((long)((b << 9) + (c4 << 2))) * 4096 + hw;
        out[zo] = v.x; out[zo + 4096] = v.y; out[zo + 8192] = v.z; out[zo + 12288] = v.w;
    }
}

// ---------------- final: loss = 1.25 * (sum(bd1)/1024 + sum||z||^2) / numel ----------------
__global__ __launch_bounds__(1024) void vq_final(const float* __restrict__ bd1,
    const float* __restrict__ zpart, float* __restrict__ out) {
    int t = threadIdx.x;
    double s = 0.0;
#pragma unroll
    for (int i = 0; i < 64; ++i) s += (double)bd1[t + (i << 10)];
    s *= (1.0 / 1024.0);
#pragma unroll
    for (int i = 0; i < 8; ++i) s += (double)zpart[t + (i << 10)];
#pragma unroll
    for (int off = 32; off > 0; off >>= 1) s += __shfl_xor(s, off);
    __shared__ double pd[16];
    if ((t & 63) == 0) pd[t >> 6] = s;
    __syncthreads();
    if (t == 0) {
        double tot = 0.0;
#pragma unroll
        for (int i = 0; i < 16; ++i) tot += pd[i];
        out[ZQ_ELEMS] = (float)(1.25 * tot / 33554432.0);
    }
}

extern "C" void kernel_launch(void* const* d_in, const int* in_sizes, int n_in,
                              void* d_out, int out_size, void* d_ws, size_t ws_size,
                              hipStream_t stream) {
    const float* z  = (const float*)d_in[0];   // (16,512,64,64) fp32
    const float* cb = (const float*)d_in[1];   // (1024,512) fp32
    float* out = (float*)d_out;                // [z_q | loss | indices(float)]
    char* ws = (char*)d_ws;

    float* ynorm = (float*)(ws + 1024);                   // 4 KB
    int*   ws_idx = (int*)(ws + 8192);                    // 256 KB -> ends 264K
    float* bd1   = (float*)(ws + 272 * 1024);             // 256 KB
    float* bd2   = (float*)(ws + 528 * 1024);             // 256 KB
    int*   bj2   = (int*)(ws + 784 * 1024);               // 256 KB
    float* zpart = (float*)(ws + 1040 * 1024);            // 32 KB
    unsigned short* Bf = (unsigned short*)(ws + (2L << 20));   // 1 MB hi-only
    const size_t base = 4L << 20;
    unsigned short* Ah = (unsigned short*)(ws + base);

    // pick M-phasing from available workspace (deterministic in ws_size)
    int nphase = 1;
    while (nphase < 16) {
        size_t Asz = (size_t)(65536 / nphase) * 512 * 2;  // hi-only bytes
        if (base + Asz <= ws_size) break;
        nphase <<= 1;
    }

    vq_prep<<<N_E, 64, 0, stream>>>(cb, ynorm);
    vq_prepB<<<64, 256, 0, stream>>>(cb, Bf);
    int PM = 65536 / nphase;
    for (int p = 0; p < nphase; ++p) {
        vq_pack<<<8192 / nphase, 256, 0, stream>>>(z, Ah, zpart,
                                                   p * (16 / nphase),
                                                   p * (8192 / nphase));
        vq_dist<<<PM / 64, 256, 0, stream>>>(Ah, Bf, ynorm, ws_idx,
                                             out + ZQ_ELEMS + 1, bd1, bd2, bj2, p * PM);
    }
    vq_refine<<<1024, 256, 0, stream>>>(z, cb, ynorm, bd2, bj2, ws_idx,
                                        out + ZQ_ELEMS + 1, bd1);
    vq_gather<<<NVEC / 256 * 32, 256, 0, stream>>>(cb, ws_idx, out);
    vq_final<<<1, 1024, 0, stream>>>(bd1, zpart, out);
}